// Round 1
// 327.158 us; speedup vs baseline: 1.0169x; 1.0169x over previous
//
#include <hip/hip_runtime.h>

// SAGAN self-attention, B=4, C=512, Cp=64, N=64*64=4096. fp32 in/out
// (runtime-detected). proj/outproj unchanged (16x16x32 MFMA). rowstats/pv
// rewritten: 32x32x16 MFMA, fragments streamed straight from global (L2-
// resident), zero LDS in main loops, no bank conflicts, no barriers.
// pv uses cvt_pk_bf16 + permlane32_swap (T12) to turn the S-tile C-layout
// into the PV A-fragment in-register. 1/l_i pre-folded into V (scalehx).
// pv i-split (2-way) reduced via LDS within block -> 2 opT buffers summed
// by outproj (no global atomics, no opT memset).

#define NB 4
#define CC 512
#define CP 64
#define NN 4096

typedef __attribute__((ext_vector_type(8))) short short8;
typedef __attribute__((ext_vector_type(4))) float floatx4;
typedef __attribute__((ext_vector_type(16))) float floatx16;

#define MFMA32(A, B, C) __builtin_amdgcn_mfma_f32_32x32x16_bf16((A), (B), (C), 0, 0, 0)

__device__ __forceinline__ float bf2f_u(unsigned short h) {
    return __uint_as_float((unsigned)h << 16);
}
__device__ __forceinline__ float bf16lo(unsigned v) { return __uint_as_float(v << 16); }
__device__ __forceinline__ float bf16hi(unsigned v) { return __uint_as_float(v & 0xffff0000u); }
__device__ __forceinline__ unsigned short f2bf(float f) {
    unsigned u = __float_as_uint(f);
    u += 0x7fffu + ((u >> 16) & 1u);   // RNE
    return (unsigned short)(u >> 16);
}
__device__ __forceinline__ unsigned pack2bf(float a, float b) {
    return (unsigned)f2bf(a) | ((unsigned)f2bf(b) << 16);
}
__device__ __forceinline__ float ldS(const void* p, long i, int f32) {
    return f32 ? ((const float*)p)[i] : bf2f_u(((const unsigned short*)p)[i]);
}
__device__ __forceinline__ float2 ld2(const void* p, long i, int f32) {
    if (f32) return *reinterpret_cast<const float2*>((const float*)p + i);
    unsigned v = *reinterpret_cast<const unsigned*>((const unsigned short*)p + i);
    return make_float2(bf16lo(v), bf16hi(v));
}
__device__ __forceinline__ float4 ld4(const void* p, long i, int f32) {
    if (f32) return *reinterpret_cast<const float4*>((const float*)p + i);
    uint2 v = *reinterpret_cast<const uint2*>((const unsigned short*)p + i);
    return make_float4(bf16lo(v.x), bf16hi(v.x), bf16lo(v.y), bf16hi(v.y));
}
__device__ __forceinline__ short8 frag8(const void* p, long i, int f32) {
    uint4 au;
    if (f32) {
        float4 v0 = *reinterpret_cast<const float4*>((const float*)p + i);
        float4 v1 = *reinterpret_cast<const float4*>((const float*)p + i + 4);
        au.x = pack2bf(v0.x, v0.y); au.y = pack2bf(v0.z, v0.w);
        au.z = pack2bf(v1.x, v1.y); au.w = pack2bf(v1.z, v1.w);
    } else {
        au = *reinterpret_cast<const uint4*>((const unsigned short*)p + i);
    }
    return *reinterpret_cast<short8*>(&au);
}
__device__ __forceinline__ short8 as_s8(uint4 v) { return *reinterpret_cast<short8*>(&v); }
__device__ __forceinline__ floatx16 zero16() {
    floatx16 z;
    #pragma unroll
    for (int i = 0; i < 16; ++i) z[i] = 0.f;
    return z;
}
__device__ __forceinline__ unsigned cvtpk_bf16(float a, float b) {
    unsigned r;
    asm("v_cvt_pk_bf16_f32 %0, %1, %2" : "=v"(r) : "v"(a), "v"(b));
    return r;
}
__device__ __forceinline__ void pl32swap(unsigned &a, unsigned &b) {
    // D.lanes[32:63] <-> S.lanes[0:31]
    asm("v_permlane32_swap_b32 %0, %1" : "+v"(a), "+v"(b));
}

// ---------------------------------------------------------------------------
// dtype detector: 1 if fp32, 0 if bf16.
// ---------------------------------------------------------------------------
__global__ __launch_bounds__(256) void detect_kernel(
    const unsigned* __restrict__ x, int* __restrict__ flag)
{
    __shared__ int red[256];
    const int t = threadIdx.x;
    int bad = 0;
    for (int i = t; i < 4096; i += 256) {
        unsigned w = x[i];
        float f0 = __uint_as_float(w << 16);
        float f1 = __uint_as_float(w & 0xffff0000u);
        float a0 = fabsf(f0), a1 = fabsf(f1);
        if (!(a0 <= 1e3f) || (f0 != 0.f && a0 < 1e-20f)) bad++;
        if (!(a1 <= 1e3f) || (f1 != 0.f && a1 < 1e-20f)) bad++;
    }
    red[t] = bad;
    __syncthreads();
    for (int s = 128; s > 0; s >>= 1) { if (t < s) red[t] += red[t + s]; __syncthreads(); }
    if (t == 0) *flag = (red[0] > 64) ? 1 : 0;
}

// ---------------------------------------------------------------------------
// sigma: v = normalize(W^T u); sigma = u^T (W v); writes 1/sigma.
// ---------------------------------------------------------------------------
__global__ __launch_bounds__(512) void sigma_kernel(
    const void* __restrict__ Wf, const void* __restrict__ Wg,
    const void* __restrict__ Wh, const void* __restrict__ Wv,
    const void* __restrict__ uf, const void* __restrict__ ug,
    const void* __restrict__ uh, const void* __restrict__ uv,
    const int* __restrict__ dflag, float* __restrict__ sig)
{
    const int f32 = *dflag;
    const int w = blockIdx.x;
    const void* W;
    const void* u;
    int R, Cc, sh;
    if (w == 0)      { W = Wf; u = uf; R = 64;  Cc = 512; sh = 9; }
    else if (w == 1) { W = Wg; u = ug; R = 64;  Cc = 512; sh = 9; }
    else if (w == 2) { W = Wh; u = uh; R = 64;  Cc = 512; sh = 9; }
    else             { W = Wv; u = uv; R = 512; Cc = 64;  sh = 6; }

    __shared__ float us[512];
    __shared__ float vs[512];
    __shared__ float red[512];
    const int t = threadIdx.x;

    if (t < R) us[t] = ldS(u, t, f32);
    __syncthreads();

    if (t < Cc) {
        float a = 0.f;
        for (int i = 0; i < R; ++i) a += ldS(W, (long)(i << sh) + t, f32) * us[i];
        vs[t] = a;
    }
    __syncthreads();

    red[t] = (t < Cc) ? vs[t] * vs[t] : 0.f;
    __syncthreads();
    for (int s = 256; s > 0; s >>= 1) { if (t < s) red[t] += red[t + s]; __syncthreads(); }
    const float inv = 1.f / (sqrtf(red[0]) + 1e-12f);
    __syncthreads();
    if (t < Cc) vs[t] *= inv;
    __syncthreads();

    float a = 0.f;
    const int total = R * Cc;
    const int mask = Cc - 1;
    for (int idx = t; idx < total; idx += 512)
        a += us[idx >> sh] * ldS(W, idx, f32) * vs[idx & mask];
    red[t] = a;
    __syncthreads();
    for (int s = 256; s > 0; s >>= 1) { if (t < s) red[t] += red[t + s]; __syncthreads(); }
    if (t == 0) sig[w] = 1.f / red[0];
}

// ---------------------------------------------------------------------------
// proj (MFMA): out^T[n][c] = sum_k x^T[n][k] * (W/sigma)^T[k][c].
// ---------------------------------------------------------------------------
__global__ __launch_bounds__(256) void proj_kernel(
    const void* __restrict__ x,
    const void* __restrict__ Wf,
    const void* __restrict__ Wg,
    const void* __restrict__ Wh,
    const int* __restrict__ dflag,
    const float* __restrict__ sig,
    unsigned short* __restrict__ fxT, unsigned short* __restrict__ gxT,
    unsigned short* __restrict__ hx)
{
    const int f32 = *dflag;
    const int n0 = blockIdx.x * 64;
    const int b  = blockIdx.y;
    const int wi = blockIdx.z;
    const void* __restrict__ W = (wi == 0) ? Wf : ((wi == 1) ? Wg : Wh);
    const float scale = sig[wi];

    __shared__ unsigned short Wl[64][72];   // [c][kk], 144B rows

    const int t = threadIdx.x;
    const int wv = t >> 6, l = t & 63, l15 = l & 15, quad = l >> 4;
    const int n = n0 + 16 * wv + l15;

    floatx4 acc[4];
    #pragma unroll
    for (int ct = 0; ct < 4; ++ct) acc[ct] = (floatx4){0.f, 0.f, 0.f, 0.f};

    for (int kc = 0; kc < CC; kc += 64) {
        #pragma unroll
        for (int idx = t; idx < 2048; idx += 256) {
            int c  = idx >> 5;
            int kk = (idx & 31) * 2;
            float2 v = ld2(W, (long)c * CC + kc + kk, f32);
            *reinterpret_cast<unsigned*>(&Wl[c][kk]) = pack2bf(v.x * scale, v.y * scale);
        }
        __syncthreads();

        #pragma unroll
        for (int ks = 0; ks < 2; ++ks) {
            const int kbase = kc + ks * 32 + quad * 8;
            float xv[8];
            #pragma unroll
            for (int j = 0; j < 8; ++j)
                xv[j] = ldS(x, ((long)b * CC + kbase + j) * NN + n, f32);
            uint4 au;
            au.x = pack2bf(xv[0], xv[1]); au.y = pack2bf(xv[2], xv[3]);
            au.z = pack2bf(xv[4], xv[5]); au.w = pack2bf(xv[6], xv[7]);
            short8 a = *reinterpret_cast<short8*>(&au);
            #pragma unroll
            for (int ct = 0; ct < 4; ++ct) {
                short8 bfr = *reinterpret_cast<const short8*>(
                    &Wl[ct * 16 + l15][ks * 32 + quad * 8]);
                acc[ct] = __builtin_amdgcn_mfma_f32_16x16x32_bf16(a, bfr, acc[ct], 0, 0, 0);
            }
        }
        __syncthreads();
    }

    if (wi < 2) {
        unsigned short* __restrict__ dstT = (wi == 0) ? fxT : gxT;
        #pragma unroll
        for (int ct = 0; ct < 4; ++ct)
            #pragma unroll
            for (int r = 0; r < 4; ++r)
                dstT[((size_t)b * NN + n0 + 16 * wv + quad * 4 + r) * 64 + ct * 16 + l15] =
                    f2bf(acc[ct][r]);
    } else {
        #pragma unroll
        for (int ct = 0; ct < 4; ++ct) {
            uint2 o;
            o.x = pack2bf(acc[ct][0], acc[ct][1]);
            o.y = pack2bf(acc[ct][2], acc[ct][3]);
            *reinterpret_cast<uint2*>(
                &hx[((size_t)b * CP + ct * 16 + l15) * NN + n0 + 16 * wv + quad * 4]) = o;
        }
    }
}

// ---------------------------------------------------------------------------
// rowstats (32x32x16 MFMA, frags from global, no LDS, no barriers):
// rl[b,i] += sum_j exp(S_ij). Block = 4 waves, each wave owns 32 i-rows,
// sweeps 512 j (NN/8 per jsplit). A-frag (fx, wave's i-rows) hoisted once;
// B-frags (gx) streamed double-buffered.
// A/B frag layout (32x32x16): row = lane&31, k = (lane>>5)*8 + e.
// C/D layout: col = lane&31, row = (reg&3)+8*(reg>>2)+4*(lane>>5).
// ---------------------------------------------------------------------------
__global__ __launch_bounds__(256, 4) void rowstats_kernel(
    const unsigned short* __restrict__ fxT, const unsigned short* __restrict__ gxT,
    float* __restrict__ rl)
{
    const int t = threadIdx.x;
    const int w = t >> 6, l = t & 63, l31 = l & 31, hi = l >> 5;
    const int b = blockIdx.z;
    const int i0 = blockIdx.x * 128 + w * 32;
    const int jbase = blockIdx.y * (NN / 8);

    const unsigned short* fA = fxT + ((size_t)b * NN + i0 + l31) * CP + (hi << 3);
    uint4 af[4];
    #pragma unroll
    for (int kc = 0; kc < 4; ++kc)
        af[kc] = *reinterpret_cast<const uint4*>(fA + kc * 16);

    const unsigned short* gB = gxT + ((size_t)b * NN + jbase + l31) * CP + (hi << 3);

    float suml[16];
    #pragma unroll
    for (int r = 0; r < 16; ++r) suml[r] = 0.f;

    uint4 bf0[4], bf1[4];
    auto loadB = [&](uint4* bf, int jt) {
        const unsigned short* p = gB + (size_t)jt * 32 * CP;
        #pragma unroll
        for (int kc = 0; kc < 4; ++kc)
            bf[kc] = *reinterpret_cast<const uint4*>(p + kc * 16);
    };
    auto bodyR = [&](uint4* bf) {
        floatx16 s = zero16();
        #pragma unroll
        for (int kc = 0; kc < 4; ++kc)
            s = MFMA32(as_s8(af[kc]), as_s8(bf[kc]), s);
        #pragma unroll
        for (int r = 0; r < 16; ++r) suml[r] += __expf(s[r]);
    };

    loadB(bf0, 0);
    for (int jt = 0; jt < 16; jt += 2) {
        loadB(bf1, jt + 1);
        bodyR(bf0);
        if (jt + 2 < 16) loadB(bf0, jt + 2);
        bodyR(bf1);
    }

    // reduce over the 32 lanes of each half (distinct j columns)
    #pragma unroll
    for (int r = 0; r < 16; ++r) {
        float v = suml[r];
        v += __shfl_xor(v, 1);
        v += __shfl_xor(v, 2);
        v += __shfl_xor(v, 4);
        v += __shfl_xor(v, 8);
        v += __shfl_xor(v, 16);
        suml[r] = v;
    }
    if (l31 == 0) {
        #pragma unroll
        for (int r = 0; r < 16; ++r) {
            int row = (r & 3) + 8 * (r >> 2) + 4 * hi;
            atomicAdd(&rl[(size_t)b * NN + i0 + row], suml[r]);
        }
    }
}

// ---------------------------------------------------------------------------
// scalehx: hxs[c][i] = hx[c][i] / rl[i]  (folds softmax denom into V).
// ---------------------------------------------------------------------------
__global__ __launch_bounds__(256) void scalehx_kernel(
    const unsigned short* __restrict__ hx, const float* __restrict__ rl,
    unsigned short* __restrict__ hxs)
{
    const size_t base = ((size_t)blockIdx.x * 256 + threadIdx.x) * 8;
    const int n = (int)(base & (NN - 1));
    const int b = (int)(base >> 12) >> 6;   // base / (NN*CP)
    uint4 v = *reinterpret_cast<const uint4*>(hx + base);
    const float* rp = rl + (size_t)b * NN + n;
    float4 r0 = *reinterpret_cast<const float4*>(rp);
    float4 r1 = *reinterpret_cast<const float4*>(rp + 4);
    uint4 ov;
    ov.x = pack2bf(bf16lo(v.x) / r0.x, bf16hi(v.x) / r0.y);
    ov.y = pack2bf(bf16lo(v.y) / r0.z, bf16hi(v.y) / r0.w);
    ov.z = pack2bf(bf16lo(v.z) / r1.x, bf16hi(v.z) / r1.y);
    ov.w = pack2bf(bf16lo(v.w) / r1.z, bf16hi(v.w) / r1.w);
    *reinterpret_cast<uint4*>(hxs + base) = ov;
}

// ---------------------------------------------------------------------------
// pv (32x32x16 MFMA): opT[b,j,c] = sum_i exp(S_ij) * hxs[c,i], for the
// block's i half-range. Block = 4 waves, ALL own the same 64-j strip (2
// sub-tiles of 32), each sweeps a disjoint 512-i range; partial O tiles
// combined via LDS atomics, written to opT[isb] (plain stores, no global
// atomics). S-tile: mfma(A=fx_i, B=gx_j) -> lane holds E[i-rows][j=lane&31].
// E -> PV A-frag via cvt_pk_bf16 pairs (e0,e1)/(e4,e5) + permlane32_swap:
// after swap(u0=pk(e0,e1), u2=pk(e4,e5)): u0 = {lo:(i0,i1), hi:(i8,i9)},
// u2 = {lo:(i4,i5), hi:(i12,i13)} = dwords 0,2 of the k-chunk-0 A-frag.
// ---------------------------------------------------------------------------
__global__ __launch_bounds__(256, 2) void pv_kernel(
    const unsigned short* __restrict__ fxT, const unsigned short* __restrict__ gxT,
    const unsigned short* __restrict__ hxs,
    float* __restrict__ opT0, float* __restrict__ opT1)
{
    const int t = threadIdx.x;
    const int w = t >> 6, l = t & 63, l31 = l & 31, hi = l >> 5;
    const int b = blockIdx.z;
    const int j0 = blockIdx.x * 64;
    const int isb = blockIdx.y;
    const int ibase = isb * (NN / 2) + w * (NN / 8);

    __shared__ float red[64 * 64];

    // hoist gx B-frags (S-MFMA B operand), rows j0+sub*32+l31
    uint4 qf0[4], qf1[4];
    {
        const unsigned short* g0 = gxT + ((size_t)b * NN + j0 + l31) * CP + (hi << 3);
        const unsigned short* g1 = g0 + 32 * CP;
        #pragma unroll
        for (int kc = 0; kc < 4; ++kc) {
            qf0[kc] = *reinterpret_cast<const uint4*>(g0 + kc * 16);
            qf1[kc] = *reinterpret_cast<const uint4*>(g1 + kc * 16);
        }
    }

    floatx16 acc00 = zero16(), acc01 = zero16();
    floatx16 acc10 = zero16(), acc11 = zero16();

    const unsigned short* fbase = fxT + ((size_t)b * NN + ibase + l31) * CP + (hi << 3);
    const unsigned short* vb0 = hxs + ((size_t)b * CP + l31) * NN + ibase + (hi << 3);
    const unsigned short* vb1 = vb0 + 32 * NN;

    uint4 af0[4], af1[4], vf[4];
    auto loadA = [&](uint4* af, int it) {
        const unsigned short* p = fbase + (size_t)it * 32 * CP;
        #pragma unroll
        for (int kc = 0; kc < 4; ++kc)
            af[kc] = *reinterpret_cast<const uint4*>(p + kc * 16);
    };
    auto loadV = [&](int it) {
        const int off = it * 32;
        vf[0] = *reinterpret_cast<const uint4*>(vb0 + off);       // ct0 ch0
        vf[1] = *reinterpret_cast<const uint4*>(vb0 + off + 16);  // ct0 ch1
        vf[2] = *reinterpret_cast<const uint4*>(vb1 + off);       // ct1 ch0
        vf[3] = *reinterpret_cast<const uint4*>(vb1 + off + 16);  // ct1 ch1
    };
    auto body = [&](uint4* af) {
        #pragma unroll
        for (int sub = 0; sub < 2; ++sub) {
            uint4* qf = sub ? qf1 : qf0;
            floatx16 s = zero16();
            #pragma unroll
            for (int kc = 0; kc < 4; ++kc)
                s = MFMA32(as_s8(af[kc]), as_s8(qf[kc]), s);
            float e[16];
            #pragma unroll
            for (int r = 0; r < 16; ++r) e[r] = __expf(s[r]);
            unsigned u0 = cvtpk_bf16(e[0], e[1]);
            unsigned u1 = cvtpk_bf16(e[2], e[3]);
            unsigned u2 = cvtpk_bf16(e[4], e[5]);
            unsigned u3 = cvtpk_bf16(e[6], e[7]);
            pl32swap(u0, u2);
            pl32swap(u1, u3);
            uint4 pa0 = make_uint4(u0, u1, u2, u3);      // k-chunk i 0..15
            unsigned u4 = cvtpk_bf16(e[8], e[9]);
            unsigned u5 = cvtpk_bf16(e[10], e[11]);
            unsigned u6 = cvtpk_bf16(e[12], e[13]);
            unsigned u7 = cvtpk_bf16(e[14], e[15]);
            pl32swap(u4, u6);
            pl32swap(u5, u7);
            uint4 pa1 = make_uint4(u4, u5, u6, u7);      // k-chunk i 16..31
            floatx16& a0 = sub ? acc10 : acc00;
            floatx16& a1 = sub ? acc11 : acc01;
            a0 = MFMA32(as_s8(pa0), as_s8(vf[0]), a0);
            a0 = MFMA32(as_s8(pa1), as_s8(vf[1]), a0);
            a1 = MFMA32(as_s8(pa0), as_s8(vf[2]), a1);
            a1 = MFMA32(as_s8(pa1), as_s8(vf[3]), a1);
        }
    };

    loadA(af0, 0);
    for (int it = 0; it < 16; it += 2) {
        loadV(it);
        loadA(af1, it + 1);
        body(af0);
        loadV(it + 1);
        if (it + 2 < 16) loadA(af0, it + 2);
        body(af1);
    }

    // block-level reduce of the 4 waves' partial O tiles
    #pragma unroll
    for (int q = 0; q < 4; ++q)
        *reinterpret_cast<float4*>(&red[(q * 256 + t) * 4]) = make_float4(0.f, 0.f, 0.f, 0.f);
    __syncthreads();
    #pragma unroll
    for (int r = 0; r < 16; ++r) {
        int row = (r & 3) + 8 * (r >> 2) + 4 * hi;
        atomicAdd(&red[row * 64 + l31],              acc00[r]);
        atomicAdd(&red[row * 64 + 32 + l31],         acc01[r]);
        atomicAdd(&red[(32 + row) * 64 + l31],       acc10[r]);
        atomicAdd(&red[(32 + row) * 64 + 32 + l31],  acc11[r]);
    }
    __syncthreads();
    float* dst = (isb ? opT1 : opT0) + ((size_t)b * NN + j0) * CP;
    #pragma unroll
    for (int q = 0; q < 4; ++q) {
        int o = (q * 256 + t) * 4;
        *reinterpret_cast<float4*>(dst + o) = *reinterpret_cast<const float4*>(&red[o]);
    }
}

// ---------------------------------------------------------------------------
// outproj (MFMA): y^T[n][co] = scale * sum_cp (opT0+opT1)[n][cp] Wv^T[cp][co] + x.
// ---------------------------------------------------------------------------
__global__ __launch_bounds__(256) void outproj_kernel(
    const void* __restrict__ x,
    const void* __restrict__ Wv,
    const void* __restrict__ gamma,
    const int* __restrict__ dflag,
    const float* __restrict__ sig,
    const float* __restrict__ opT0,
    const float* __restrict__ opT1,
    void* __restrict__ y)
{
    const int f32 = *dflag;
    const int n0     = blockIdx.x * 64;
    const int cobase = blockIdx.y * 128;
    const int b      = blockIdx.z;
    const int t = threadIdx.x;
    const int wv = t >> 6, l = t & 63, l15 = l & 15, quad = l >> 4;
    const float scale = ldS(gamma, 0, f32) * sig[3];

    floatx4 acc[4][2];
    #pragma unroll
    for (int ns = 0; ns < 4; ++ns)
        #pragma unroll
        for (int ct = 0; ct < 2; ++ct) acc[ns][ct] = (floatx4){0.f, 0.f, 0.f, 0.f};

    #pragma unroll
    for (int ks = 0; ks < 2; ++ks) {
        const int kb = ks * 32 + quad * 8;
        short8 a[4];
        #pragma unroll
        for (int ns = 0; ns < 4; ++ns) {
            const long off = ((long)b * NN + n0 + 16 * ns + l15) * CP + kb;
            float4 x0 = *reinterpret_cast<const float4*>(opT0 + off);
            float4 x1 = *reinterpret_cast<const float4*>(opT0 + off + 4);
            float4 y0 = *reinterpret_cast<const float4*>(opT1 + off);
            float4 y1 = *reinterpret_cast<const float4*>(opT1 + off + 4);
            uint4 au;
            au.x = pack2bf(x0.x + y0.x, x0.y + y0.y);
            au.y = pack2bf(x0.z + y0.z, x0.w + y0.w);
            au.z = pack2bf(x1.x + y1.x, x1.y + y1.y);
            au.w = pack2bf(x1.z + y1.z, x1.w + y1.w);
            a[ns] = *reinterpret_cast<short8*>(&au);
        }
        #pragma unroll
        for (int ct = 0; ct < 2; ++ct) {
            const int co = cobase + 32 * wv + 16 * ct + l15;
            short8 bfr = frag8(Wv, (long)co * CP + kb, f32);
            #pragma unroll
            for (int ns = 0; ns < 4; ++ns)
                acc[ns][ct] = __builtin_amdgcn_mfma_f32_16x16x32_bf16(a[ns], bfr, acc[ns][ct], 0, 0, 0);
        }
    }

    #pragma unroll
    for (int ns = 0; ns < 4; ++ns)
        #pragma unroll
        for (int ct = 0; ct < 2; ++ct) {
            const int co = cobase + 32 * wv + 16 * ct + l15;
            const long base = ((long)b * CC + co) * NN + n0 + 16 * ns + quad * 4;
            float4 xv = ld4(x, base, f32);
            float o0 = fmaf(scale, acc[ns][ct][0], xv.x);
            float o1 = fmaf(scale, acc[ns][ct][1], xv.y);
            float o2 = fmaf(scale, acc[ns][ct][2], xv.z);
            float o3 = fmaf(scale, acc[ns][ct][3], xv.w);
            if (f32) {
                *reinterpret_cast<float4*>((float*)y + base) = make_float4(o0, o1, o2, o3);
            } else {
                uint2 o;
                o.x = pack2bf(o0, o1);
                o.y = pack2bf(o2, o3);
                *reinterpret_cast<uint2*>((unsigned short*)y + base) = o;
            }
        }
}

// ---------------------------------------------------------------------------
extern "C" void kernel_launch(void* const* d_in, const int* in_sizes, int n_in,
                              void* d_out, int out_size, void* d_ws, size_t ws_size,
                              hipStream_t stream)
{
    const void* x  = d_in[0];
    const void* Wf = d_in[1];
    const void* Wg = d_in[2];
    const void* Wh = d_in[3];
    const void* Wv = d_in[4];
    const void* uf = d_in[5];
    const void* ug = d_in[6];
    const void* uh = d_in[7];
    const void* uv = d_in[8];
    const void* gm = d_in[9];

    // ws: dfl | sig | rl (64KB) | opT0 (4MB) | opT1 (4MB) | fxT | gxT | hx | hxs (2MB bf16 each)
    char* base = (char*)d_ws;
    int*   dfl = (int*)(base);
    float* sig = (float*)(base + 512);
    float* rl  = (float*)(base + 1024);
    float* opT0 = (float*)(base + 1024 + 65536);
    float* opT1 = opT0 + (size_t)NB * NN * CP;
    unsigned short* fxT = (unsigned short*)(opT1 + (size_t)NB * NN * CP);
    unsigned short* gxT = fxT + (size_t)NB * CP * NN;
    unsigned short* hx  = gxT + (size_t)NB * CP * NN;
    unsigned short* hxs = hx + (size_t)NB * CP * NN;

    hipMemsetAsync(rl, 0, (size_t)NB * NN * sizeof(float), stream);

    hipLaunchKernelGGL(detect_kernel, dim3(1), dim3(256), 0, stream,
                       (const unsigned*)x, dfl);
    hipLaunchKernelGGL(sigma_kernel, dim3(4), dim3(512), 0, stream,
                       Wf, Wg, Wh, Wv, uf, ug, uh, uv, dfl, sig);
    hipLaunchKernelGGL(proj_kernel, dim3(NN / 64, NB, 3), dim3(256), 0, stream,
                       x, Wf, Wg, Wh, dfl, sig, fxT, gxT, hx);
    hipLaunchKernelGGL(rowstats_kernel, dim3(NN / 128, 8, NB), dim3(256), 0, stream,
                       fxT, gxT, rl);
    hipLaunchKernelGGL(scalehx_kernel, dim3((NB * CP * NN) / 2048), dim3(256), 0, stream,
                       hx, rl, hxs);
    hipLaunchKernelGGL(pv_kernel, dim3(NN / 64, 2, NB), dim3(256), 0, stream,
                       fxT, gxT, hxs, opT0, opT1);
    hipLaunchKernelGGL(outproj_kernel, dim3(NN / 64, CC / 128, NB), dim3(256), 0, stream,
                       x, Wv, gm, dfl, sig, opT0, opT1, d_out);
}

// Round 2
// 244.383 us; speedup vs baseline: 1.3613x; 1.3387x over previous
//
#include <hip/hip_runtime.h>

// SAGAN self-attention, B=4, C=512, Cp=64, N=64*64=4096. fp32 in/out
// (runtime-detected). proj/outproj: 16x16x32 MFMA. rowstats/pv: 32x32x16
// MFMA with fx/gx/hx stored in *fragment-order* global layouts so every
// main-loop load is lane-linear (coalesced 1KB/instr) -- no 64-line
// gathers, no LDS in main loops, no barriers. pv folds 1/l_i via
// broadcast rl loads + v_rcp (scalehx kernel eliminated). sigma =
// ||W^T u||^2/(||W^T u||+eps) -- single matvec, fully unrolled.
//
// fxF/gxF layout (A/B frag, 32-row n-tiles, K=Cp):
//   off(b,tile,kc,l,e) = (((b*128+tile)*4+kc)*64+l)*8+e
//   content: (n = tile*32 + (l&31), c = kc*16 + (l>>5)*8 + e)
// hxF layout (PV B-frag, 32-i tiles):
//   off(b,tile,ich,part,l,e) = ((((b*128+tile)*2+ich)*2+part)*64+l)*8+e
//   content: (c = part*32 + (l&31), i = tile*32 + ich*16 + (l>>5)*8 + e)

#define NB 4
#define CC 512
#define CP 64
#define NN 4096

typedef __attribute__((ext_vector_type(8))) short short8;
typedef __attribute__((ext_vector_type(4))) float floatx4;
typedef __attribute__((ext_vector_type(16))) float floatx16;

#define MFMA32(A, B, C) __builtin_amdgcn_mfma_f32_32x32x16_bf16((A), (B), (C), 0, 0, 0)

__device__ __forceinline__ float bf2f_u(unsigned short h) {
    return __uint_as_float((unsigned)h << 16);
}
__device__ __forceinline__ float bf16lo(unsigned v) { return __uint_as_float(v << 16); }
__device__ __forceinline__ float bf16hi(unsigned v) { return __uint_as_float(v & 0xffff0000u); }
__device__ __forceinline__ unsigned short f2bf(float f) {
    unsigned u = __float_as_uint(f);
    u += 0x7fffu + ((u >> 16) & 1u);   // RNE
    return (unsigned short)(u >> 16);
}
__device__ __forceinline__ unsigned pack2bf(float a, float b) {
    return (unsigned)f2bf(a) | ((unsigned)f2bf(b) << 16);
}
__device__ __forceinline__ float ldS(const void* p, long i, int f32) {
    return f32 ? ((const float*)p)[i] : bf2f_u(((const unsigned short*)p)[i]);
}
__device__ __forceinline__ float2 ld2(const void* p, long i, int f32) {
    if (f32) return *reinterpret_cast<const float2*>((const float*)p + i);
    unsigned v = *reinterpret_cast<const unsigned*>((const unsigned short*)p + i);
    return make_float2(bf16lo(v), bf16hi(v));
}
__device__ __forceinline__ float4 ld4(const void* p, long i, int f32) {
    if (f32) return *reinterpret_cast<const float4*>((const float*)p + i);
    uint2 v = *reinterpret_cast<const uint2*>((const unsigned short*)p + i);
    return make_float4(bf16lo(v.x), bf16hi(v.x), bf16lo(v.y), bf16hi(v.y));
}
__device__ __forceinline__ short8 frag8(const void* p, long i, int f32) {
    uint4 au;
    if (f32) {
        float4 v0 = *reinterpret_cast<const float4*>((const float*)p + i);
        float4 v1 = *reinterpret_cast<const float4*>((const float*)p + i + 4);
        au.x = pack2bf(v0.x, v0.y); au.y = pack2bf(v0.z, v0.w);
        au.z = pack2bf(v1.x, v1.y); au.w = pack2bf(v1.z, v1.w);
    } else {
        au = *reinterpret_cast<const uint4*>((const unsigned short*)p + i);
    }
    return *reinterpret_cast<short8*>(&au);
}
__device__ __forceinline__ short8 as_s8(uint4 v) { return *reinterpret_cast<short8*>(&v); }
__device__ __forceinline__ floatx16 zero16() {
    floatx16 z;
    #pragma unroll
    for (int i = 0; i < 16; ++i) z[i] = 0.f;
    return z;
}
__device__ __forceinline__ unsigned cvtpk_bf16(float a, float b) {
    unsigned r;
    asm("v_cvt_pk_bf16_f32 %0, %1, %2" : "=v"(r) : "v"(a), "v"(b));
    return r;
}
__device__ __forceinline__ void pl32swap(unsigned &a, unsigned &b) {
    asm("v_permlane32_swap_b32 %0, %1" : "+v"(a), "+v"(b));
}
__device__ __forceinline__ float rcpf(float x) {
    float r;
    asm("v_rcp_f32 %0, %1" : "=v"(r) : "v"(x));
    return r;
}

// ---------------------------------------------------------------------------
// dtype detector: 1 if fp32, 0 if bf16.
// ---------------------------------------------------------------------------
__global__ __launch_bounds__(256) void detect_kernel(
    const unsigned* __restrict__ x, int* __restrict__ flag)
{
    __shared__ int red[256];
    const int t = threadIdx.x;
    int bad = 0;
    for (int i = t; i < 4096; i += 256) {
        unsigned w = x[i];
        float f0 = __uint_as_float(w << 16);
        float f1 = __uint_as_float(w & 0xffff0000u);
        float a0 = fabsf(f0), a1 = fabsf(f1);
        if (!(a0 <= 1e3f) || (f0 != 0.f && a0 < 1e-20f)) bad++;
        if (!(a1 <= 1e3f) || (f1 != 0.f && a1 < 1e-20f)) bad++;
    }
    red[t] = bad;
    __syncthreads();
    for (int s = 128; s > 0; s >>= 1) { if (t < s) red[t] += red[t + s]; __syncthreads(); }
    if (t == 0) *flag = (red[0] > 64) ? 1 : 0;
}

// ---------------------------------------------------------------------------
// sigma: a = W^T u; sigma = ||a||^2 / (||a||+eps); writes 1/sigma.
// (u @ W @ normalize(W^T u) == ||W^T u||^2/(||W^T u||+eps) exactly.)
// Literal-bound unrolled loops -> all 64 loads/thread in flight at once.
// ---------------------------------------------------------------------------
__global__ __launch_bounds__(512) void sigma_kernel(
    const void* __restrict__ Wf, const void* __restrict__ Wg,
    const void* __restrict__ Wh, const void* __restrict__ Wv,
    const void* __restrict__ uf, const void* __restrict__ ug,
    const void* __restrict__ uh, const void* __restrict__ uv,
    const int* __restrict__ dflag, float* __restrict__ sig)
{
    const int f32 = *dflag;
    const int w = blockIdx.x;
    const void* W;
    const void* u;
    if (w == 0)      { W = Wf; u = uf; }
    else if (w == 1) { W = Wg; u = ug; }
    else if (w == 2) { W = Wh; u = uh; }
    else             { W = Wv; u = uv; }

    __shared__ float us[512];
    __shared__ float red[512];
    const int t = threadIdx.x;
    float S;

    if (w < 3) {
        // W: 64x512, u: 64. a_c = sum_i W[i][c]*u[i], c = t.
        if (t < 64) us[t] = ldS(u, t, f32);
        __syncthreads();
        float a = 0.f;
        #pragma unroll
        for (int i = 0; i < 64; ++i)
            a = fmaf(ldS(W, (long)i * 512 + t, f32), us[i], a);
        red[t] = a * a;
        __syncthreads();
        #pragma unroll
        for (int s = 256; s > 0; s >>= 1) {
            if (t < s) red[t] += red[t + s];
            __syncthreads();
        }
        S = red[0];
    } else {
        // W: 512x64, u: 512. a_c = sum_i W[i][c]*u[i]; 8 row-groups/col.
        us[t] = ldS(u, t, f32);
        __syncthreads();
        const int g = t >> 6, c = t & 63;
        float a = 0.f;
        #pragma unroll
        for (int k = 0; k < 64; ++k) {
            int i = g + k * 8;
            a = fmaf(ldS(W, (long)i * 64 + c, f32), us[i], a);
        }
        red[t] = a;
        __syncthreads();
        #pragma unroll
        for (int s = 256; s >= 64; s >>= 1) {
            if (t < s) red[t] += red[t + s];
            __syncthreads();
        }
        float ac = (t < 64) ? red[t] : 0.f;
        __syncthreads();
        red[t] = ac * ac;
        __syncthreads();
        #pragma unroll
        for (int s = 256; s > 0; s >>= 1) {
            if (t < s) red[t] += red[t + s];
            __syncthreads();
        }
        S = red[0];
    }
    if (t == 0) sig[w] = (sqrtf(S) + 1e-12f) / S;
}

// ---------------------------------------------------------------------------
// proj (MFMA): out^T[n][c] = sum_k x^T[n][k] * (W/sigma)^T[k][c].
// Epilogue writes fragment-order layouts (fxF/gxF for wi<2, hxF for wi=2).
// ---------------------------------------------------------------------------
__global__ __launch_bounds__(256) void proj_kernel(
    const void* __restrict__ x,
    const void* __restrict__ Wf,
    const void* __restrict__ Wg,
    const void* __restrict__ Wh,
    const int* __restrict__ dflag,
    const float* __restrict__ sig,
    unsigned short* __restrict__ fxF, unsigned short* __restrict__ gxF,
    unsigned short* __restrict__ hxF)
{
    const int f32 = *dflag;
    const int n0 = blockIdx.x * 64;
    const int b  = blockIdx.y;
    const int wi = blockIdx.z;
    const void* __restrict__ W = (wi == 0) ? Wf : ((wi == 1) ? Wg : Wh);
    const float scale = sig[wi];

    __shared__ unsigned short Wl[64][72];   // [c][kk], 144B rows

    const int t = threadIdx.x;
    const int wv = t >> 6, l = t & 63, l15 = l & 15, quad = l >> 4;
    const int n = n0 + 16 * wv + l15;

    floatx4 acc[4];
    #pragma unroll
    for (int ct = 0; ct < 4; ++ct) acc[ct] = (floatx4){0.f, 0.f, 0.f, 0.f};

    for (int kc = 0; kc < CC; kc += 64) {
        #pragma unroll
        for (int idx = t; idx < 2048; idx += 256) {
            int c  = idx >> 5;
            int kk = (idx & 31) * 2;
            float2 v = ld2(W, (long)c * CC + kc + kk, f32);
            *reinterpret_cast<unsigned*>(&Wl[c][kk]) = pack2bf(v.x * scale, v.y * scale);
        }
        __syncthreads();

        #pragma unroll
        for (int ks = 0; ks < 2; ++ks) {
            const int kbase = kc + ks * 32 + quad * 8;
            float xv[8];
            #pragma unroll
            for (int j = 0; j < 8; ++j)
                xv[j] = ldS(x, ((long)b * CC + kbase + j) * NN + n, f32);
            uint4 au;
            au.x = pack2bf(xv[0], xv[1]); au.y = pack2bf(xv[2], xv[3]);
            au.z = pack2bf(xv[4], xv[5]); au.w = pack2bf(xv[6], xv[7]);
            short8 a = *reinterpret_cast<short8*>(&au);
            #pragma unroll
            for (int ct = 0; ct < 4; ++ct) {
                short8 bfr = *reinterpret_cast<const short8*>(
                    &Wl[ct * 16 + l15][ks * 32 + quad * 8]);
                acc[ct] = __builtin_amdgcn_mfma_f32_16x16x32_bf16(a, bfr, acc[ct], 0, 0, 0);
            }
        }
        __syncthreads();
    }

    // D: row = quad*4+r (n-local), col = l15 (c-local within ct tile)
    if (wi < 2) {
        unsigned short* __restrict__ dstF = (wi == 0) ? fxF : gxF;
        const int nloc = 16 * wv + quad * 4;
        #pragma unroll
        for (int ct = 0; ct < 4; ++ct)
            #pragma unroll
            for (int r = 0; r < 4; ++r) {
                int nn = n0 + nloc + r;
                size_t off = (((size_t)(b * 128 + (nn >> 5)) * 4 + ct) * 64
                              + (l15 >> 3) * 32 + (nn & 31)) * 8 + (l15 & 7);
                dstF[off] = f2bf(acc[ct][r]);
            }
    } else {
        const int tile = (n0 + 16 * wv) >> 5;
        const int ich  = wv & 1;
        const int ksub = quad >> 1;
        const int ebase = (quad & 1) * 4;
        #pragma unroll
        for (int ct = 0; ct < 4; ++ct) {
            int part = ct >> 1;
            int lloc = ksub * 32 + (ct & 1) * 16 + l15;
            size_t off = ((((size_t)(b * 128 + tile) * 2 + ich) * 2 + part) * 64
                          + lloc) * 8 + ebase;
            uint2 o;
            o.x = pack2bf(acc[ct][0], acc[ct][1]);
            o.y = pack2bf(acc[ct][2], acc[ct][3]);
            *reinterpret_cast<uint2*>(&hxF[off]) = o;
        }
    }
}

// ---------------------------------------------------------------------------
// rowstats (32x32x16 MFMA, coalesced frag loads, no LDS, no barriers):
// rl[b,i] += sum_j exp(S_ij). 4 waves/block, wave owns 32 i-rows, sweeps
// 512 j. A-frag hoisted; B-frags double-buffered, lane-linear loads.
// ---------------------------------------------------------------------------
__global__ __launch_bounds__(256, 4) void rowstats_kernel(
    const unsigned short* __restrict__ fxF, const unsigned short* __restrict__ gxF,
    float* __restrict__ rl)
{
    const int t = threadIdx.x;
    const int w = t >> 6, l = t & 63, l31 = l & 31, hi = l >> 5;
    const int b = blockIdx.z;
    const int i0 = blockIdx.x * 128 + w * 32;
    const int jbase = blockIdx.y * (NN / 8);

    const unsigned short* fA = fxF + ((size_t)(b * 128 + (i0 >> 5))) * 2048 + (size_t)l * 8;
    uint4 af[4];
    #pragma unroll
    for (int kc = 0; kc < 4; ++kc)
        af[kc] = *reinterpret_cast<const uint4*>(fA + kc * 512);

    const unsigned short* gB = gxF + ((size_t)(b * 128 + (jbase >> 5))) * 2048 + (size_t)l * 8;

    float suml[16];
    #pragma unroll
    for (int r = 0; r < 16; ++r) suml[r] = 0.f;

    uint4 bf0[4], bf1[4];
    auto loadB = [&](uint4* bf, int jt) {
        const unsigned short* p = gB + (size_t)jt * 2048;
        #pragma unroll
        for (int kc = 0; kc < 4; ++kc)
            bf[kc] = *reinterpret_cast<const uint4*>(p + kc * 512);
    };
    auto bodyR = [&](uint4* bf) {
        floatx16 s = zero16();
        #pragma unroll
        for (int kc = 0; kc < 4; ++kc)
            s = MFMA32(as_s8(af[kc]), as_s8(bf[kc]), s);
        #pragma unroll
        for (int r = 0; r < 16; ++r) suml[r] += __expf(s[r]);
    };

    loadB(bf0, 0);
    for (int jt = 0; jt < 16; jt += 2) {
        loadB(bf1, jt + 1);
        bodyR(bf0);
        if (jt + 2 < 16) loadB(bf0, jt + 2);
        bodyR(bf1);
    }

    #pragma unroll
    for (int r = 0; r < 16; ++r) {
        float v = suml[r];
        v += __shfl_xor(v, 1);
        v += __shfl_xor(v, 2);
        v += __shfl_xor(v, 4);
        v += __shfl_xor(v, 8);
        v += __shfl_xor(v, 16);
        suml[r] = v;
    }
    if (l31 == 0) {
        #pragma unroll
        for (int r = 0; r < 16; ++r) {
            int row = (r & 3) + 8 * (r >> 2) + 4 * hi;
            atomicAdd(&rl[(size_t)b * NN + i0 + row], suml[r]);
        }
    }
}

// ---------------------------------------------------------------------------
// pv (32x32x16 MFMA): opT[b,j,c] = sum_i exp(S_ij)/l_i * hx[c,i] over the
// block's i half-range. All loads lane-linear (frag layouts); rl loaded
// broadcast per i-tile, folded via v_rcp. cvt_pk+permlane32_swap turns the
// S-tile C-layout into the PV A-frag in-register. 4-wave i-split reduced
// via LDS atomics -> plain stores into opT[isb].
// ---------------------------------------------------------------------------
__global__ __launch_bounds__(256, 2) void pv_kernel(
    const unsigned short* __restrict__ fxF, const unsigned short* __restrict__ gxF,
    const unsigned short* __restrict__ hxF, const float* __restrict__ rl,
    float* __restrict__ opT0, float* __restrict__ opT1)
{
    const int t = threadIdx.x;
    const int w = t >> 6, l = t & 63, l31 = l & 31, hi = l >> 5;
    const int b = blockIdx.z;
    const int j0 = blockIdx.x * 64;
    const int isb = blockIdx.y;
    const int ibase = isb * (NN / 2) + w * (NN / 8);

    __shared__ float red[64 * 64];

    // hoist gx B-frags (S-MFMA B operand), tiles j0/32 and j0/32+1
    uint4 qf0[4], qf1[4];
    {
        const unsigned short* gq = gxF + ((size_t)(b * 128 + (j0 >> 5))) * 2048 + (size_t)l * 8;
        #pragma unroll
        for (int kc = 0; kc < 4; ++kc) {
            qf0[kc] = *reinterpret_cast<const uint4*>(gq + kc * 512);
            qf1[kc] = *reinterpret_cast<const uint4*>(gq + 2048 + kc * 512);
        }
    }

    floatx16 acc00 = zero16(), acc01 = zero16();
    floatx16 acc10 = zero16(), acc11 = zero16();

    const unsigned short* fb = fxF + ((size_t)(b * 128 + (ibase >> 5))) * 2048 + (size_t)l * 8;
    const unsigned short* vb = hxF + ((size_t)(b * 128 + (ibase >> 5))) * 2048 + (size_t)l * 8;
    const float* rbase = rl + (size_t)b * NN + ibase + (hi << 2);

    uint4 af0[4], af1[4], vf[4];
    auto loadA = [&](uint4* af, int it) {
        const unsigned short* p = fb + (size_t)it * 2048;
        #pragma unroll
        for (int kc = 0; kc < 4; ++kc)
            af[kc] = *reinterpret_cast<const uint4*>(p + kc * 512);
    };
    auto loadV = [&](int it) {
        const unsigned short* p = vb + (size_t)it * 2048;
        vf[0] = *reinterpret_cast<const uint4*>(p);           // ich0 part0 (k 0..15, c 0..31)
        vf[1] = *reinterpret_cast<const uint4*>(p + 1024);    // ich1 part0 (k16..31, c 0..31)
        vf[2] = *reinterpret_cast<const uint4*>(p + 512);     // ich0 part1 (k 0..15, c32..63)
        vf[3] = *reinterpret_cast<const uint4*>(p + 1536);    // ich1 part1 (k16..31, c32..63)
    };
    auto body = [&](uint4* af, int it) {
        // 1/l_i for this i-tile: i = it*32 + (r&3) + 8*(r>>2) + 4*hi (broadcast loads)
        const float* rp = rbase + it * 32;
        float4 rv0 = *reinterpret_cast<const float4*>(rp);
        float4 rv1 = *reinterpret_cast<const float4*>(rp + 8);
        float4 rv2 = *reinterpret_cast<const float4*>(rp + 16);
        float4 rv3 = *reinterpret_cast<const float4*>(rp + 24);
        float ri[16];
        ri[0] = rcpf(rv0.x); ri[1] = rcpf(rv0.y); ri[2] = rcpf(rv0.z); ri[3] = rcpf(rv0.w);
        ri[4] = rcpf(rv1.x); ri[5] = rcpf(rv1.y); ri[6] = rcpf(rv1.z); ri[7] = rcpf(rv1.w);
        ri[8] = rcpf(rv2.x); ri[9] = rcpf(rv2.y); ri[10] = rcpf(rv2.z); ri[11] = rcpf(rv2.w);
        ri[12] = rcpf(rv3.x); ri[13] = rcpf(rv3.y); ri[14] = rcpf(rv3.z); ri[15] = rcpf(rv3.w);
        #pragma unroll
        for (int sub = 0; sub < 2; ++sub) {
            uint4* qf = sub ? qf1 : qf0;
            floatx16 s = zero16();
            #pragma unroll
            for (int kc = 0; kc < 4; ++kc)
                s = MFMA32(as_s8(af[kc]), as_s8(qf[kc]), s);
            float e[16];
            #pragma unroll
            for (int r = 0; r < 16; ++r) e[r] = __expf(s[r]) * ri[r];
            unsigned u0 = cvtpk_bf16(e[0], e[1]);
            unsigned u1 = cvtpk_bf16(e[2], e[3]);
            unsigned u2 = cvtpk_bf16(e[4], e[5]);
            unsigned u3 = cvtpk_bf16(e[6], e[7]);
            pl32swap(u0, u2);
            pl32swap(u1, u3);
            uint4 pa0 = make_uint4(u0, u1, u2, u3);      // P k-chunk i 0..15
            unsigned u4 = cvtpk_bf16(e[8], e[9]);
            unsigned u5 = cvtpk_bf16(e[10], e[11]);
            unsigned u6 = cvtpk_bf16(e[12], e[13]);
            unsigned u7 = cvtpk_bf16(e[14], e[15]);
            pl32swap(u4, u6);
            pl32swap(u5, u7);
            uint4 pa1 = make_uint4(u4, u5, u6, u7);      // P k-chunk i 16..31
            floatx16& a0 = sub ? acc10 : acc00;
            floatx16& a1 = sub ? acc11 : acc01;
            a0 = MFMA32(as_s8(pa0), as_s8(vf[0]), a0);
            a0 = MFMA32(as_s8(pa1), as_s8(vf[1]), a0);
            a1 = MFMA32(as_s8(pa0), as_s8(vf[2]), a1);
            a1 = MFMA32(as_s8(pa1), as_s8(vf[3]), a1);
        }
    };

    loadA(af0, 0);
    for (int it = 0; it < 16; it += 2) {
        loadV(it);
        loadA(af1, it + 1);
        body(af0, it);
        loadV(it + 1);
        if (it + 2 < 16) loadA(af0, it + 2);
        body(af1, it + 1);
    }

    // block-level reduce of the 4 waves' partial O tiles
    #pragma unroll
    for (int q = 0; q < 4; ++q)
        *reinterpret_cast<float4*>(&red[(q * 256 + t) * 4]) = make_float4(0.f, 0.f, 0.f, 0.f);
    __syncthreads();
    #pragma unroll
    for (int r = 0; r < 16; ++r) {
        int row = (r & 3) + 8 * (r >> 2) + 4 * hi;
        atomicAdd(&red[row * 64 + l31],              acc00[r]);
        atomicAdd(&red[row * 64 + 32 + l31],         acc01[r]);
        atomicAdd(&red[(32 + row) * 64 + l31],       acc10[r]);
        atomicAdd(&red[(32 + row) * 64 + 32 + l31],  acc11[r]);
    }
    __syncthreads();
    float* dst = (isb ? opT1 : opT0) + ((size_t)b * NN + j0) * CP;
    #pragma unroll
    for (int q = 0; q < 4; ++q) {
        int o = (q * 256 + t) * 4;
        *reinterpret_cast<float4*>(dst + o) = *reinterpret_cast<const float4*>(&red[o]);
    }
}

// ---------------------------------------------------------------------------
// outproj (MFMA): y^T[n][co] = scale * sum_cp (opT0+opT1)[n][cp] Wv^T[cp][co] + x.
// ---------------------------------------------------------------------------
__global__ __launch_bounds__(256) void outproj_kernel(
    const void* __restrict__ x,
    const void* __restrict__ Wv,
    const void* __restrict__ gamma,
    const int* __restrict__ dflag,
    const float* __restrict__ sig,
    const float* __restrict__ opT0,
    const float* __restrict__ opT1,
    void* __restrict__ y)
{
    const int f32 = *dflag;
    const int n0     = blockIdx.x * 64;
    const int cobase = blockIdx.y * 128;
    const int b      = blockIdx.z;
    const int t = threadIdx.x;
    const int wv = t >> 6, l = t & 63, l15 = l & 15, quad = l >> 4;
    const float scale = ldS(gamma, 0, f32) * sig[3];

    floatx4 acc[4][2];
    #pragma unroll
    for (int ns = 0; ns < 4; ++ns)
        #pragma unroll
        for (int ct = 0; ct < 2; ++ct) acc[ns][ct] = (floatx4){0.f, 0.f, 0.f, 0.f};

    #pragma unroll
    for (int ks = 0; ks < 2; ++ks) {
        const int kb = ks * 32 + quad * 8;
        short8 a[4];
        #pragma unroll
        for (int ns = 0; ns < 4; ++ns) {
            const long off = ((long)b * NN + n0 + 16 * ns + l15) * CP + kb;
            float4 x0 = *reinterpret_cast<const float4*>(opT0 + off);
            float4 x1 = *reinterpret_cast<const float4*>(opT0 + off + 4);
            float4 y0 = *reinterpret_cast<const float4*>(opT1 + off);
            float4 y1 = *reinterpret_cast<const float4*>(opT1 + off + 4);
            uint4 au;
            au.x = pack2bf(x0.x + y0.x, x0.y + y0.y);
            au.y = pack2bf(x0.z + y0.z, x0.w + y0.w);
            au.z = pack2bf(x1.x + y1.x, x1.y + y1.y);
            au.w = pack2bf(x1.z + y1.z, x1.w + y1.w);
            a[ns] = *reinterpret_cast<short8*>(&au);
        }
        #pragma unroll
        for (int ct = 0; ct < 2; ++ct) {
            const int co = cobase + 32 * wv + 16 * ct + l15;
            short8 bfr = frag8(Wv, (long)co * CP + kb, f32);
            #pragma unroll
            for (int ns = 0; ns < 4; ++ns)
                acc[ns][ct] = __builtin_amdgcn_mfma_f32_16x16x32_bf16(a[ns], bfr, acc[ns][ct], 0, 0, 0);
        }
    }

    #pragma unroll
    for (int ns = 0; ns < 4; ++ns)
        #pragma unroll
        for (int ct = 0; ct < 2; ++ct) {
            const int co = cobase + 32 * wv + 16 * ct + l15;
            const long base = ((long)b * CC + co) * NN + n0 + 16 * ns + quad * 4;
            float4 xv = ld4(x, base, f32);
            float o0 = fmaf(scale, acc[ns][ct][0], xv.x);
            float o1 = fmaf(scale, acc[ns][ct][1], xv.y);
            float o2 = fmaf(scale, acc[ns][ct][2], xv.z);
            float o3 = fmaf(scale, acc[ns][ct][3], xv.w);
            if (f32) {
                *reinterpret_cast<float4*>((float*)y + base) = make_float4(o0, o1, o2, o3);
            } else {
                uint2 o;
                o.x = pack2bf(o0, o1);
                o.y = pack2bf(o2, o3);
                *reinterpret_cast<uint2*>((unsigned short*)y + base) = o;
            }
        }
}

// ---------------------------------------------------------------------------
extern "C" void kernel_launch(void* const* d_in, const int* in_sizes, int n_in,
                              void* d_out, int out_size, void* d_ws, size_t ws_size,
                              hipStream_t stream)
{
    const void* x  = d_in[0];
    const void* Wf = d_in[1];
    const void* Wg = d_in[2];
    const void* Wh = d_in[3];
    const void* Wv = d_in[4];
    const void* uf = d_in[5];
    const void* ug = d_in[6];
    const void* uh = d_in[7];
    const void* uv = d_in[8];
    const void* gm = d_in[9];

    // ws: dfl | sig | rl (64KB) | opT0 (4MB) | opT1 (4MB) | fxF | gxF | hxF (2MB bf16 each)
    char* base = (char*)d_ws;
    int*   dfl = (int*)(base);
    float* sig = (float*)(base + 512);
    float* rl  = (float*)(base + 1024);
    float* opT0 = (float*)(base + 1024 + 65536);
    float* opT1 = opT0 + (size_t)NB * NN * CP;
    unsigned short* fxF = (unsigned short*)(opT1 + (size_t)NB * NN * CP);
    unsigned short* gxF = fxF + (size_t)NB * CP * NN;
    unsigned short* hxF = gxF + (size_t)NB * CP * NN;

    hipMemsetAsync(rl, 0, (size_t)NB * NN * sizeof(float), stream);

    hipLaunchKernelGGL(detect_kernel, dim3(1), dim3(256), 0, stream,
                       (const unsigned*)x, dfl);
    hipLaunchKernelGGL(sigma_kernel, dim3(4), dim3(512), 0, stream,
                       Wf, Wg, Wh, Wv, uf, ug, uh, uv, dfl, sig);
    hipLaunchKernelGGL(proj_kernel, dim3(NN / 64, NB, 3), dim3(256), 0, stream,
                       x, Wf, Wg, Wh, dfl, sig, fxF, gxF, hxF);
    hipLaunchKernelGGL(rowstats_kernel, dim3(NN / 128, 8, NB), dim3(256), 0, stream,
                       fxF, gxF, rl);
    hipLaunchKernelGGL(pv_kernel, dim3(NN / 64, 2, NB), dim3(256), 0, stream,
                       fxF, gxF, hxF, rl, opT0, opT1);
    hipLaunchKernelGGL(outproj_kernel, dim3(NN / 64, CC / 128, NB), dim3(256), 0, stream,
                       x, Wv, gm, dfl, sig, opT0, opT1, d_out);
}